// Round 2
// baseline (1033.877 us; speedup 1.0000x reference)
//
#include <hip/hip_runtime.h>

// B=128, S=2048, H=512.
//   d_in: 0 query[128,1,512] f32, 1 keys[128,2048,512] f32, 2 Wa[512,512], 3 ba[512],
//         4 Ua[512,512], 5 bu[512], 6 Va[1,512], 7 bv[1]
//   d_out: context[128,1,512] (65536 f32) then weights[128,1,2048] (262144 f32)
//
// Plan A (ws >= 269 MB): pre-convert keys+Ua to bf16 in ws; m97-style GEMM with
// global_load_lds width=16 (zero staging VALU); context reads bf16 keys.
// Plan B fallback: round-1 kernels (in-loop conversion).

#define KEYS_N 134217728ull  // 128*2048*512
#define UA_N   262144ull     // 512*512

typedef __attribute__((ext_vector_type(8))) short bf16x8;
typedef __attribute__((ext_vector_type(4))) float f32x4;

static __device__ inline short f2bf(float f) {
  unsigned u = __float_as_uint(f);
  unsigned r = (u + 0x7FFFu + ((u >> 16) & 1u)) >> 16;  // RNE
  return (short)r;
}

static __device__ inline void store8(short* dst, float4 a, float4 b) {
  union { bf16x8 v; short s[8]; } u;
  u.s[0] = f2bf(a.x); u.s[1] = f2bf(a.y); u.s[2] = f2bf(a.z); u.s[3] = f2bf(a.w);
  u.s[4] = f2bf(b.x); u.s[5] = f2bf(b.y); u.s[6] = f2bf(b.z); u.s[7] = f2bf(b.w);
  *(bf16x8*)dst = u.v;
}

static __device__ inline void async16(const void* g, void* l) {
  // global -> LDS direct copy, 16B/lane; LDS dest = uniform base + lane*16
  __builtin_amdgcn_global_load_lds((const __attribute__((address_space(1))) void*)g,
                                   (__attribute__((address_space(3))) void*)l, 16, 0, 0);
}

// ---------------- fp32 -> bf16 bulk convert (8 elems/thread) ----------------
__global__ __launch_bounds__(256) void convert_kernel(const float* __restrict__ in,
                                                      short* __restrict__ out) {
  const size_t i = ((size_t)blockIdx.x * 256 + threadIdx.x) * 8;
  const float4* p = (const float4*)(in + i);
  float4 a = p[0], b = p[1];
  store8(out + i, a, b);
}

// ---------------- K1: wq = query.Wa^T + ba + bu -> wqb [128][512] ----------------
__global__ __launch_bounds__(512) void wq_kernel(const float* __restrict__ query,
                                                 const float* __restrict__ Wa,
                                                 const float* __restrict__ ba,
                                                 const float* __restrict__ bu,
                                                 float* __restrict__ wqb) {
  const int b = blockIdx.x;
  const int o = threadIdx.x;
  __shared__ float qs[512];
  qs[o] = query[(b << 9) + o];
  __syncthreads();
  const float4* w4 = (const float4*)(Wa + (size_t)o * 512);
  float acc = 0.f;
#pragma unroll 4
  for (int h = 0; h < 128; ++h) {
    float4 w = w4[h];
    acc += w.x * qs[4 * h] + w.y * qs[4 * h + 1] + w.z * qs[4 * h + 2] + w.w * qs[4 * h + 3];
  }
  wqb[(b << 9) + o] = acc + ba[o] + bu[o];
}

// ---------------- K2 (Plan A): bf16 GEMM + tanh + Va-dot -> partial scores ----------------
__global__ __launch_bounds__(256) void score_gemm_bf16(const short* __restrict__ keys,
                                                       const short* __restrict__ ua,
                                                       const float* __restrict__ wqb,
                                                       const float* __restrict__ Va,
                                                       float* __restrict__ scores) {
  __shared__ short As[128][32];  // unpadded: required by global_load_lds lane order
  __shared__ short Bs[128][32];

  // XCD swizzle: id%8 = XCD (round-robin); the 4 n-blocks of one m-stripe are
  // adjacent slots on the same XCD -> keys rows re-read from that XCD's L2.
  const int id = blockIdx.x;
  const int s = id >> 3;
  const int m0 = ((id & 7) * 256 + (s >> 2)) * 128;  // m-block 0..2047
  const int n0 = (s & 3) * 128;
  const int b = m0 >> 11;

  const int tid = threadIdx.x;
  const int lane = tid & 63;
  const int wave = tid >> 6;
  const int wm = (wave >> 1) * 64;
  const int wn = (wave & 1) * 64;
  const int mlane = lane & 15;
  const int quad = lane >> 4;

  const int lrow = lane >> 2;       // 0..15: row within 16-row chunk
  const int lcol = (lane & 3) * 8;  // 0,8,16,24 shorts = 16B units

  f32x4 acc[4][4];
  f32x4 zero = {0.f, 0.f, 0.f, 0.f};
#pragma unroll
  for (int i = 0; i < 4; ++i)
#pragma unroll
    for (int j = 0; j < 4; ++j) acc[i][j] = zero;

  const short* gA = keys + (size_t)(m0 + wave * 32 + lrow) * 512 + lcol;
  const short* gB = ua + (size_t)(n0 + wave * 32 + lrow) * 512 + lcol;

  for (int k0 = 0; k0 < 512; k0 += 32) {
    __syncthreads();
    async16(gA + k0, &As[wave * 32][0]);
    async16(gA + k0 + 16 * 512, &As[wave * 32 + 16][0]);
    async16(gB + k0, &Bs[wave * 32][0]);
    async16(gB + k0 + 16 * 512, &Bs[wave * 32 + 16][0]);
    __syncthreads();

    bf16x8 af[4], bfr[4];
#pragma unroll
    for (int i = 0; i < 4; ++i) af[i] = *(const bf16x8*)&As[wm + i * 16 + mlane][quad * 8];
#pragma unroll
    for (int j = 0; j < 4; ++j) bfr[j] = *(const bf16x8*)&Bs[wn + j * 16 + mlane][quad * 8];
#pragma unroll
    for (int i = 0; i < 4; ++i)
#pragma unroll
      for (int j = 0; j < 4; ++j)
        acc[i][j] = __builtin_amdgcn_mfma_f32_16x16x32_bf16(af[i], bfr[j], acc[i][j], 0, 0, 0);
  }

  // Epilogue: t = tanh(acc + wqb[b,n]); partial score = sum_n Va[n]*t
  // C/D layout: col = lane&15, row = quad*4 + reg  (verified m89/m91)
  float wqv[4], vav[4];
#pragma unroll
  for (int j = 0; j < 4; ++j) {
    const int n = n0 + wn + j * 16 + mlane;
    wqv[j] = wqb[(b << 9) + n];
    vav[j] = Va[n];
  }
  float rs[4][4] = {};
#pragma unroll
  for (int j = 0; j < 4; ++j)
#pragma unroll
    for (int i = 0; i < 4; ++i)
#pragma unroll
      for (int r = 0; r < 4; ++r) {
        const float v = acc[i][j][r] + wqv[j];
        const float e = __expf(2.0f * v);
        const float t = 1.0f - 2.0f * __builtin_amdgcn_rcpf(e + 1.0f);
        rs[i][r] += vav[j] * t;
      }
#pragma unroll
  for (int i = 0; i < 4; ++i)
#pragma unroll
    for (int r = 0; r < 4; ++r) {
      float v = rs[i][r];
      v += __shfl_xor(v, 1);
      v += __shfl_xor(v, 2);
      v += __shfl_xor(v, 4);
      v += __shfl_xor(v, 8);
      if (mlane == 0) atomicAdd(&scores[m0 + wm + i * 16 + quad * 4 + r], v);
    }
}

// ---------------- K2 (Plan B fallback): round-1 fused GEMM ----------------
#define LDK 40
__global__ __launch_bounds__(256) void score_gemm(const float* __restrict__ keys,
                                                  const float* __restrict__ Ua,
                                                  const float* __restrict__ wqb,
                                                  const float* __restrict__ Va,
                                                  float* __restrict__ scores) {
  __shared__ short As[128][LDK];
  __shared__ short Bs[128][LDK];
  const int n0 = blockIdx.x * 128;
  const int m0 = blockIdx.y * 128;
  const int b = m0 >> 11;
  const int tid = threadIdx.x;
  const int lane = tid & 63;
  const int wave = tid >> 6;
  const int wm = (wave >> 1) * 64;
  const int wn = (wave & 1) * 64;
  const int mlane = lane & 15;
  const int quad = lane >> 4;
  const int sr = tid >> 2;
  const int sc = (tid & 3) * 8;

  f32x4 zero = {0.f, 0.f, 0.f, 0.f};
  f32x4 acc[4][4];
#pragma unroll
  for (int i = 0; i < 4; ++i)
#pragma unroll
    for (int j = 0; j < 4; ++j) acc[i][j] = zero;

  for (int k0 = 0; k0 < 512; k0 += 32) {
    __syncthreads();
#pragma unroll
    for (int it = 0; it < 2; ++it) {
      const int row = sr + it * 64;
      const float* pa = keys + (size_t)(m0 + row) * 512 + k0 + sc;
      const float* pb = Ua + (size_t)(n0 + row) * 512 + k0 + sc;
      float4 a0 = *(const float4*)pa;
      float4 a1 = *(const float4*)(pa + 4);
      float4 b0 = *(const float4*)pb;
      float4 b1 = *(const float4*)(pb + 4);
      store8(&As[row][sc], a0, a1);
      store8(&Bs[row][sc], b0, b1);
    }
    __syncthreads();
    bf16x8 af[4], bfr[4];
#pragma unroll
    for (int i = 0; i < 4; ++i) af[i] = *(const bf16x8*)&As[wm + i * 16 + mlane][quad * 8];
#pragma unroll
    for (int j = 0; j < 4; ++j) bfr[j] = *(const bf16x8*)&Bs[wn + j * 16 + mlane][quad * 8];
#pragma unroll
    for (int i = 0; i < 4; ++i)
#pragma unroll
      for (int j = 0; j < 4; ++j)
        acc[i][j] = __builtin_amdgcn_mfma_f32_16x16x32_bf16(af[i], bfr[j], acc[i][j], 0, 0, 0);
  }
  float wqv[4], vav[4];
#pragma unroll
  for (int j = 0; j < 4; ++j) {
    const int n = n0 + wn + j * 16 + mlane;
    wqv[j] = wqb[(b << 9) + n];
    vav[j] = Va[n];
  }
  float rs[4][4] = {};
#pragma unroll
  for (int j = 0; j < 4; ++j)
#pragma unroll
    for (int i = 0; i < 4; ++i)
#pragma unroll
      for (int r = 0; r < 4; ++r) {
        const float v = acc[i][j][r] + wqv[j];
        const float e = __expf(2.0f * v);
        const float t = 1.0f - 2.0f * __builtin_amdgcn_rcpf(e + 1.0f);
        rs[i][r] += vav[j] * t;
      }
#pragma unroll
  for (int i = 0; i < 4; ++i)
#pragma unroll
    for (int r = 0; r < 4; ++r) {
      float v = rs[i][r];
      v += __shfl_xor(v, 1);
      v += __shfl_xor(v, 2);
      v += __shfl_xor(v, 4);
      v += __shfl_xor(v, 8);
      if (mlane == 0) atomicAdd(&scores[m0 + wm + i * 16 + quad * 4 + r], v);
    }
}

// ---------------- K3: softmax over S (in place) + zero context region ----------------
__global__ __launch_bounds__(256) void softmax_kernel(float* __restrict__ sw,
                                                      float* __restrict__ context) {
  const int b = blockIdx.x;
  const int t = threadIdx.x;
  context[(b << 9) + t] = 0.f;
  context[(b << 9) + 256 + t] = 0.f;

  float* row = sw + (size_t)(b << 11);
  float4 x0 = *(float4*)(row + t * 8);
  float4 x1 = *(float4*)(row + t * 8 + 4);

  float mx = fmaxf(fmaxf(fmaxf(x0.x, x0.y), fmaxf(x0.z, x0.w)),
                   fmaxf(fmaxf(x1.x, x1.y), fmaxf(x1.z, x1.w)));
#pragma unroll
  for (int d = 1; d < 64; d <<= 1) mx = fmaxf(mx, __shfl_xor(mx, d));

  __shared__ float smax[4], ssum[4];
  const int wave = t >> 6, lane = t & 63;
  if (lane == 0) smax[wave] = mx;
  __syncthreads();
  mx = fmaxf(fmaxf(smax[0], smax[1]), fmaxf(smax[2], smax[3]));

  float e[8];
  e[0] = __expf(x0.x - mx); e[1] = __expf(x0.y - mx);
  e[2] = __expf(x0.z - mx); e[3] = __expf(x0.w - mx);
  e[4] = __expf(x1.x - mx); e[5] = __expf(x1.y - mx);
  e[6] = __expf(x1.z - mx); e[7] = __expf(x1.w - mx);
  float s = e[0] + e[1] + e[2] + e[3] + e[4] + e[5] + e[6] + e[7];
#pragma unroll
  for (int d = 1; d < 64; d <<= 1) s += __shfl_xor(s, d);
  if (lane == 0) ssum[wave] = s;
  __syncthreads();
  s = ssum[0] + ssum[1] + ssum[2] + ssum[3];
  const float inv = 1.0f / s;

  float4 y0, y1;
  y0.x = e[0] * inv; y0.y = e[1] * inv; y0.z = e[2] * inv; y0.w = e[3] * inv;
  y1.x = e[4] * inv; y1.y = e[5] * inv; y1.z = e[6] * inv; y1.w = e[7] * inv;
  *(float4*)(row + t * 8) = y0;
  *(float4*)(row + t * 8 + 4) = y1;
}

// ---------------- K4 (Plan A): context = weights . keys_bf16 ----------------
__global__ __launch_bounds__(256) void context_bf16(const short* __restrict__ keys,
                                                    const float* __restrict__ weights,
                                                    float* __restrict__ context) {
  const int b = blockIdx.x >> 2;
  const int chunk = blockIdx.x & 3;
  const int t = threadIdx.x;
  const int hg = t & 63;
  const int sl = t >> 6;

  float acc[8] = {0.f, 0.f, 0.f, 0.f, 0.f, 0.f, 0.f, 0.f};
  const float* wrow = weights + (size_t)(b << 11) + (chunk << 9);
  const short* kbase = keys + ((size_t)(b << 11) + (chunk << 9)) * 512 + hg * 8;
  for (int s = sl; s < 512; s += 4) {
    const float w = wrow[s];
    union { bf16x8 v; unsigned short u[8]; } kv;
    kv.v = *(const bf16x8*)(kbase + (size_t)s * 512);
#pragma unroll
    for (int j = 0; j < 8; ++j)
      acc[j] += w * __uint_as_float(((unsigned)kv.u[j]) << 16);
  }
  __shared__ float red[4][512];
  float4 r0, r1;
  r0.x = acc[0]; r0.y = acc[1]; r0.z = acc[2]; r0.w = acc[3];
  r1.x = acc[4]; r1.y = acc[5]; r1.z = acc[6]; r1.w = acc[7];
  *(float4*)&red[sl][hg * 8] = r0;
  *(float4*)&red[sl][hg * 8 + 4] = r1;
  __syncthreads();
#pragma unroll
  for (int hh = 0; hh < 2; ++hh) {
    const int h = t + hh * 256;
    const float v = red[0][h] + red[1][h] + red[2][h] + red[3][h];
    atomicAdd(&context[(b << 9) + h], v);
  }
}

// ---------------- K4 (Plan B fallback): fp32 context ----------------
__global__ __launch_bounds__(256) void context_kernel(const float* __restrict__ keys,
                                                      const float* __restrict__ weights,
                                                      float* __restrict__ context) {
  const int b = blockIdx.x >> 2;
  const int chunk = blockIdx.x & 3;
  const int t = threadIdx.x;
  const int hg = t & 63;
  const int sl = t >> 6;
  float acc[8] = {0.f, 0.f, 0.f, 0.f, 0.f, 0.f, 0.f, 0.f};
  const float* wrow = weights + (size_t)(b << 11) + (chunk << 9);
  const float* kbase = keys + ((size_t)(b << 11) + (chunk << 9)) * 512 + hg * 8;
  for (int s = sl; s < 512; s += 4) {
    const float w = wrow[s];
    const float* kp = kbase + (size_t)s * 512;
    float4 k0 = *(const float4*)kp;
    float4 k1 = *(const float4*)(kp + 4);
    acc[0] += w * k0.x; acc[1] += w * k0.y; acc[2] += w * k0.z; acc[3] += w * k0.w;
    acc[4] += w * k1.x; acc[5] += w * k1.y; acc[6] += w * k1.z; acc[7] += w * k1.w;
  }
  __shared__ float red[4][512];
  float4 r0, r1;
  r0.x = acc[0]; r0.y = acc[1]; r0.z = acc[2]; r0.w = acc[3];
  r1.x = acc[4]; r1.y = acc[5]; r1.z = acc[6]; r1.w = acc[7];
  *(float4*)&red[sl][hg * 8] = r0;
  *(float4*)&red[sl][hg * 8 + 4] = r1;
  __syncthreads();
#pragma unroll
  for (int hh = 0; hh < 2; ++hh) {
    const int h = t + hh * 256;
    const float v = red[0][h] + red[1][h] + red[2][h] + red[3][h];
    atomicAdd(&context[(b << 9) + h], v);
  }
}

extern "C" void kernel_launch(void* const* d_in, const int* in_sizes, int n_in,
                              void* d_out, int out_size, void* d_ws, size_t ws_size,
                              hipStream_t stream) {
  const float* query = (const float*)d_in[0];
  const float* keys  = (const float*)d_in[1];
  const float* Wa    = (const float*)d_in[2];
  const float* ba    = (const float*)d_in[3];
  const float* Ua    = (const float*)d_in[4];
  const float* bu    = (const float*)d_in[5];
  const float* Va    = (const float*)d_in[6];
  // d_in[7] = bv: softmax-invariant, dropped

  float* out = (float*)d_out;
  float* context = out;          // [128*512]
  float* weights = out + 65536;  // [128*2048]; doubles as scores scratch
  float* wqb = context;          // overwritten by softmax_kernel's zeroing later

  const bool planA = ws_size >= (KEYS_N + UA_N) * sizeof(short);

  hipMemsetAsync(weights, 0, (size_t)262144 * sizeof(float), stream);
  wq_kernel<<<dim3(128), dim3(512), 0, stream>>>(query, Wa, ba, bu, wqb);

  if (planA) {
    short* kbf = (short*)d_ws;
    short* ubf = kbf + KEYS_N;
    convert_kernel<<<dim3(65536), dim3(256), 0, stream>>>(keys, kbf);
    convert_kernel<<<dim3(128), dim3(256), 0, stream>>>(Ua, ubf);
    score_gemm_bf16<<<dim3(8192), dim3(256), 0, stream>>>(kbf, ubf, wqb, Va, weights);
  } else {
    score_gemm<<<dim3(4, 2048), dim3(256), 0, stream>>>(keys, Ua, wqb, Va, weights);
  }

  softmax_kernel<<<dim3(128), dim3(256), 0, stream>>>(weights, context);

  if (planA) {
    context_bf16<<<dim3(512), dim3(256), 0, stream>>>((short*)d_ws, weights, context);
  } else {
    context_kernel<<<dim3(512), dim3(256), 0, stream>>>(keys, weights, context);
  }
}